// Round 2
// baseline (209.174 us; speedup 1.0000x reference)
//
#include <hip/hip_runtime.h>

// LIF constants (match reference)
constexpr int   SEQ      = 100;
constexpr float DT_TAUI  = 0.1f;   // DT * TAU_MEM_INV
constexpr float V_TH     = 1.0f;

typedef float        f32x2 __attribute__((ext_vector_type(2)));
typedef float        f32x4 __attribute__((ext_vector_type(4)));
typedef unsigned int u32;
typedef unsigned int u32x2 __attribute__((ext_vector_type(2)));
typedef unsigned int u32x4 __attribute__((ext_vector_type(4)));

// ---------------- Pass 1: simulate LIF, emit spike bit-planes ----------------
// bits layout: u32 bits[4][N]; bit (t&31) of bits[t>>5][n] = spike(t, n).
// One thread per 2 neurons; all state in registers; 4 coalesced 8B stores.
__global__ __launch_bounds__(256) void lif_sim_bits(
    const float* __restrict__ in, u32* __restrict__ bits, int n2)
{
    int i = blockIdx.x * blockDim.x + threadIdx.x;
    if (i >= n2) return;

    f32x2 I = reinterpret_cast<const f32x2*>(in)[i];
    f32x2 v = {0.f, 0.f};
    u32x2 m0 = {0, 0}, m1 = {0, 0}, m2 = {0, 0}, m3 = {0, 0};

    // Static chunking (t>>5 = 0..3) avoids runtime-indexed register arrays
    // (rule: dynamic indexing spills to scratch).
#define LIF_CHUNK(M, CNT)                              \
    _Pragma("unroll")                                  \
    for (int k = 0; k < (CNT); ++k) {                  \
        v.x += DT_TAUI * (I.x - v.x);                  \
        v.y += DT_TAUI * (I.y - v.y);                  \
        u32 zx = (v.x > V_TH) ? 1u : 0u;               \
        u32 zy = (v.y > V_TH) ? 1u : 0u;               \
        M.x |= zx << k;                                \
        M.y |= zy << k;                                \
        v.x = zx ? 0.f : v.x;                          \
        v.y = zy ? 0.f : v.y;                          \
    }
    LIF_CHUNK(m0, 32)
    LIF_CHUNK(m1, 32)
    LIF_CHUNK(m2, 32)
    LIF_CHUNK(m3, SEQ - 96)
#undef LIF_CHUNK

    u32x2* b2 = reinterpret_cast<u32x2*>(bits);
    b2[(size_t)0 * n2 + i] = m0;
    b2[(size_t)1 * n2 + i] = m1;
    b2[(size_t)2 * n2 + i] = m2;
    b2[(size_t)3 * n2 + i] = m3;
}

// ---------------- Pass 2: linear bit-plane -> f32 expansion ------------------
// Pure streaming write, identical stream shape to the 6.6 TB/s fill kernel.
// Each thread: X4PT f32x4 stores (16B/lane, wave = 1KB contiguous);
// mask reads are coalesced 16B/lane from the L3-resident 8.4 MB bit-planes.
constexpr int X4PT = 4;  // f32x4 stores per thread

__global__ __launch_bounds__(256) void lif_expand(
    const u32* __restrict__ bits, float* __restrict__ out,
    int logN, int total4)
{
    int base = blockIdx.x * (blockDim.x * X4PT) + threadIdx.x;
#pragma unroll
    for (int k = 0; k < X4PT; ++k) {
        int j = base + k * 256;          // f32x4 index
        if (j >= total4) return;
        u32 idx = (u32)j << 2;           // float index
        u32 t   = idx >> logN;           // timestep
        u32 n   = idx & ((1u << logN) - 1u);
        u32 b   = t & 31u;
        u32x4 m = *reinterpret_cast<const u32x4*>(
            bits + ((size_t)(t >> 5) << logN) + n);
        f32x4 z;
        z.x = (float)((m.x >> b) & 1u);
        z.y = (float)((m.y >> b) & 1u);
        z.z = (float)((m.z >> b) & 1u);
        z.w = (float)((m.w >> b) & 1u);
        reinterpret_cast<f32x4*>(out)[j] = z;
    }
}

// ---------------- Fallback: round-0 single-pass (cached stores) --------------
__global__ __launch_bounds__(256) void lif_encode_kernel(
    const float* __restrict__ in, float* __restrict__ out, int n2)
{
    int i = blockIdx.x * blockDim.x + threadIdx.x;
    if (i >= n2) return;

    const f32x2* in2  = reinterpret_cast<const f32x2*>(in);
    f32x2*       out2 = reinterpret_cast<f32x2*>(out);

    f32x2 I = in2[i];
    f32x2 v = {0.f, 0.f};

    for (int t = 0; t < SEQ; ++t) {
        v.x += DT_TAUI * (I.x - v.x);
        v.y += DT_TAUI * (I.y - v.y);
        f32x2 z;
        z.x = (v.x > V_TH) ? 1.f : 0.f;
        z.y = (v.y > V_TH) ? 1.f : 0.f;
        v.x -= z.x * v.x;
        v.y -= z.y * v.y;
        out2[(size_t)t * n2 + i] = z;
    }
}

extern "C" void kernel_launch(void* const* d_in, const int* in_sizes, int n_in,
                              void* d_out, int out_size, void* d_ws, size_t ws_size,
                              hipStream_t stream)
{
    const float* in  = reinterpret_cast<const float*>(d_in[0]);
    float*       out = reinterpret_cast<float*>(d_out);
    int n  = in_sizes[0];              // 64*8192 = 524288 neurons
    int n2 = n / 2;

    bool pow2 = (n & (n - 1)) == 0;
    size_t bits_bytes = (size_t)4 * n * sizeof(u32);   // 8.4 MB

    if (pow2 && n >= 8 && d_ws != nullptr && ws_size >= bits_bytes) {
        u32* bits = reinterpret_cast<u32*>(d_ws);
        int logN = 31 - __builtin_clz((u32)n);

        int block = 256;
        int grid1 = (n2 + block - 1) / block;                 // 1024
        lif_sim_bits<<<grid1, block, 0, stream>>>(in, bits, n2);

        int total4 = (SEQ * n) / 4;                           // 13,107,200
        int per_blk = block * X4PT;
        int grid2 = (total4 + per_blk - 1) / per_blk;         // 12800
        lif_expand<<<grid2, block, 0, stream>>>(bits, out, logN, total4);
    } else {
        int block = 256;
        int grid  = (n2 + block - 1) / block;
        lif_encode_kernel<<<grid, block, 0, stream>>>(in, out, n2);
    }
}

// Round 3
// 198.784 us; speedup vs baseline: 1.0523x; 1.0523x over previous
//
#include <hip/hip_runtime.h>

// LIF constants (match reference)
constexpr int   SEQ      = 100;
constexpr float DT_TAUI  = 0.1f;   // DT * TAU_MEM_INV
constexpr float V_TH     = 1.0f;

typedef float f32x2 __attribute__((ext_vector_type(2)));
typedef float f32x4 __attribute__((ext_vector_type(4)));

// Single pass, registers only, geometry tuned for DRAM write locality:
// each block owns 2048 consecutive neurons -> every timestep it writes an
// 8 KB contiguous chunk (vs 2 KB in round 0), as 2x f32x4 (16 B/lane)
// stores. Grid = N/2048 = 256 blocks = 1 block/CU. No loads in the loop,
// so stores are fire-and-forget; the HBM drain rate is the only limiter.
__global__ __launch_bounds__(256) void lif_encode_wide(
    const float* __restrict__ in, float* __restrict__ out, int n)
{
    int tid  = threadIdx.x;
    int base4 = (blockIdx.x << 9) + tid;          // f32x4 index of group A

    const f32x4* in4 = reinterpret_cast<const f32x4*>(in);
    f32x4 Ia = in4[base4];
    f32x4 Ib = in4[base4 + 256];

    f32x4 va = {0.f, 0.f, 0.f, 0.f};
    f32x4 vb = {0.f, 0.f, 0.f, 0.f};

    f32x4* outA = reinterpret_cast<f32x4*>(out) + base4;
    int    step4 = n >> 2;                        // one plane, in f32x4 units

    for (int t = 0; t < SEQ; ++t) {
        f32x4 za, zb;
#pragma unroll
        for (int c = 0; c < 4; ++c) {
            va[c] += DT_TAUI * (Ia[c] - va[c]);
            vb[c] += DT_TAUI * (Ib[c] - vb[c]);
            float sza = (va[c] > V_TH) ? 1.f : 0.f;
            float szb = (vb[c] > V_TH) ? 1.f : 0.f;
            za[c] = sza;
            zb[c] = szb;
            va[c] = (sza != 0.f) ? 0.f : va[c];
            vb[c] = (szb != 0.f) ? 0.f : vb[c];
        }
        outA[0]   = za;
        outA[256] = zb;
        outA += step4;
    }
}

// Fallback: round-0 kernel (2 neurons/thread, cached 8B stores)
__global__ __launch_bounds__(256) void lif_encode_kernel(
    const float* __restrict__ in, float* __restrict__ out, int n2)
{
    int i = blockIdx.x * blockDim.x + threadIdx.x;
    if (i >= n2) return;

    const f32x2* in2  = reinterpret_cast<const f32x2*>(in);
    f32x2*       out2 = reinterpret_cast<f32x2*>(out);

    f32x2 I = in2[i];
    f32x2 v = {0.f, 0.f};

    for (int t = 0; t < SEQ; ++t) {
        v.x += DT_TAUI * (I.x - v.x);
        v.y += DT_TAUI * (I.y - v.y);
        f32x2 z;
        z.x = (v.x > V_TH) ? 1.f : 0.f;
        z.y = (v.y > V_TH) ? 1.f : 0.f;
        v.x -= z.x * v.x;
        v.y -= z.y * v.y;
        out2[(size_t)t * n2 + i] = z;
    }
}

extern "C" void kernel_launch(void* const* d_in, const int* in_sizes, int n_in,
                              void* d_out, int out_size, void* d_ws, size_t ws_size,
                              hipStream_t stream)
{
    const float* in  = reinterpret_cast<const float*>(d_in[0]);
    float*       out = reinterpret_cast<float*>(d_out);
    int n = in_sizes[0];               // 64*8192 = 524288 neurons

    if ((n & 2047) == 0) {
        int grid = n >> 11;            // 2048 neurons per block -> 256
        lif_encode_wide<<<grid, 256, 0, stream>>>(in, out, n);
    } else {
        int n2 = n / 2;
        int block = 256;
        int grid  = (n2 + block - 1) / block;
        lif_encode_kernel<<<grid, block, 0, stream>>>(in, out, n2);
    }
}